// Round 9
// baseline (49.896 us; speedup 1.0000x reference)
//
#include <hip/hip_runtime.h>

#define LN_EPS 1e-5f

// out[b,n,f,e] = LN(x[b,n,:])[f] * w[f,e] + (pb[f,e] + emb[f,e])
// B=4, N=4096, F=64, E=64 -> rows = 16384, 4096 fp32 outputs per row.
//
// R9 = R8 (47.7 us) minus the post-butterfly dependency tail:
// each thread computes xn at its 4 needed features directly from the
// (lane-uniform) mu/inv and pre-issued x/gamma/beta loads at f = i*16+f0,
// deleting the 4 dependent __shfl broadcasts + xn_lane from the critical
// path. cv = pb+emb is precomputed right after the table loads so the adds
// overlap the butterfly.
// Validated structure: 1 row/block, 16384 blocks, no LDS/barrier,
// wave-redundant joint butterfly, nontemporal f4 stores.

typedef float f4 __attribute__((ext_vector_type(4)));

__global__ __launch_bounds__(256) void pte_kernel(
    const float* __restrict__ x,      // [rows, 64]
    const float* __restrict__ gamma,  // [64]
    const float* __restrict__ beta,   // [64]
    const float* __restrict__ w,      // [64, 64]
    const float* __restrict__ pb,     // [64, 64]
    const float* __restrict__ emb,    // [64, 64]
    float* __restrict__ out)          // [rows, 4096]
{
    const int row  = blockIdx.x;
    const int tid  = threadIdx.x;
    const int lane = tid & 63;
    const int f0   = tid >> 4;        // this thread's feature base (0..15)

    const float* __restrict__ xr = x + (size_t)row * 64;

    // --- Critical-path loads first: own x element + the 4 xn-inputs ---
    float v = xr[lane];
    float xf[4], gf[4], bf[4];
    #pragma unroll
    for (int i = 0; i < 4; ++i) {
        int f = i * 16 + f0;          // 16 consecutive threads share f
        xf[i] = xr[f];
        gf[i] = gamma[f];
        bf[i] = beta[f];
    }

    // --- Table loads (latency-tolerant, overlap the LN reduction) ---
    const f4* __restrict__ w4 = (const f4*)w;
    const f4* __restrict__ b4 = (const f4*)pb;
    const f4* __restrict__ e4 = (const f4*)emb;

    f4 wv[4], cv[4];
    #pragma unroll
    for (int i = 0; i < 4; ++i) {
        int idx = i * 256 + tid;      // float4 index in [0,1024)
        wv[i] = w4[idx];
        cv[i] = b4[idx] + e4[idx];    // adds overlap the butterfly
    }

    // --- LayerNorm reduce (wave-redundant, joint sum/sumsq butterfly) ---
    float s  = v;
    float s2 = v * v;
    #pragma unroll
    for (int m = 1; m < 64; m <<= 1) {
        s  += __shfl_xor(s,  m, 64);
        s2 += __shfl_xor(s2, m, 64);
    }
    float mu  = s * (1.0f / 64.0f);
    float var = fmaf(-mu, mu, s2 * (1.0f / 64.0f));
    float inv = rsqrtf(var + LN_EPS);

    // --- Emit 4096 floats as 1024 nontemporal float4 stores (4 / thread) ---
    f4* __restrict__ o4 = (f4*)(out + (size_t)row * 4096);
    #pragma unroll
    for (int i = 0; i < 4; ++i) {
        float xn = fmaf((xf[i] - mu) * inv, gf[i], bf[i]);
        f4 r;
        r.x = fmaf(xn, wv[i].x, cv[i].x);
        r.y = fmaf(xn, wv[i].y, cv[i].y);
        r.z = fmaf(xn, wv[i].z, cv[i].z);
        r.w = fmaf(xn, wv[i].w, cv[i].w);
        __builtin_nontemporal_store(r, &o4[i * 256 + tid]);
    }
}

extern "C" void kernel_launch(void* const* d_in, const int* in_sizes, int n_in,
                              void* d_out, int out_size, void* d_ws, size_t ws_size,
                              hipStream_t stream) {
    const float* x     = (const float*)d_in[0];  // [4,4096,64]
    const float* gamma = (const float*)d_in[1];  // [64]
    const float* beta  = (const float*)d_in[2];  // [64]
    const float* w     = (const float*)d_in[3];  // [64,64]
    const float* pb    = (const float*)d_in[4];  // [64,64]
    const float* emb   = (const float*)d_in[5];  // [64,64]
    float* out = (float*)d_out;

    const int rows = 4 * 4096;  // B * N
    pte_kernel<<<rows, 256, 0, stream>>>(x, gamma, beta, w, pb, emb, out);
}

// Round 10
// 49.463 us; speedup vs baseline: 1.0088x; 1.0088x over previous
//
#include <hip/hip_runtime.h>

#define LN_EPS 1e-5f

// out[b,n,f,e] = LN(x[b,n,:])[f] * w[f,e] + (pb[f,e] + emb[f,e])
// B=4, N=4096, F=64, E=64 -> rows = 16384, 4096 fp32 outputs per row.
//
// R10 = R8 verbatim (best measured: 47.7 us, ~82% of demonstrated
// pure-store BW). Validated over R0-R9:
//  - one row per block, 16384 short-lived blocks (persistent/multi-row/
//    split variants: 57.6 / 61.0 / 56.3 vs 51.1).
//  - x load issued FIRST (before table loads): 51.1 -> 47.7 us.
//  - table re-fetch per block is NOT a limiter (3 falsifications).
//  - __shfl broadcast beats per-thread xn recompute (49.9 us).
//  - no LDS / no __syncthreads: wave-redundant LN + joint butterfly.
//  - nontemporal f4 stores (+6% vs plain).

typedef float f4 __attribute__((ext_vector_type(4)));

__global__ __launch_bounds__(256) void pte_kernel(
    const float* __restrict__ x,      // [rows, 64]
    const float* __restrict__ gamma,  // [64]
    const float* __restrict__ beta,   // [64]
    const float* __restrict__ w,      // [64, 64]
    const float* __restrict__ pb,     // [64, 64]
    const float* __restrict__ emb,    // [64, 64]
    float* __restrict__ out)          // [rows, 4096]
{
    const int row  = blockIdx.x;
    const int tid  = threadIdx.x;
    const int lane = tid & 63;

    // --- Critical-path load first: x row (HBM miss ~900 cyc) ---
    float v  = x[(size_t)row * 64 + lane];
    float g  = gamma[lane];
    float bt = beta[lane];

    // --- Table loads (latency-tolerant, overlap the LN reduction) ---
    const f4* __restrict__ w4 = (const f4*)w;
    const f4* __restrict__ b4 = (const f4*)pb;
    const f4* __restrict__ e4 = (const f4*)emb;

    f4 wv[4], bv[4], ev[4];
    #pragma unroll
    for (int i = 0; i < 4; ++i) {
        int idx = i * 256 + tid;      // float4 index in [0,1024)
        wv[i] = w4[idx];
        bv[i] = b4[idx];
        ev[i] = e4[idx];
    }

    // --- LayerNorm (wave-redundant, joint sum/sumsq butterfly) ---
    float s  = v;
    float s2 = v * v;
    #pragma unroll
    for (int m = 1; m < 64; m <<= 1) {
        s  += __shfl_xor(s,  m, 64);
        s2 += __shfl_xor(s2, m, 64);
    }
    float mu  = s * (1.0f / 64.0f);
    float var = fmaf(-mu, mu, s2 * (1.0f / 64.0f));
    float inv = rsqrtf(var + LN_EPS);
    float xn_lane = (v - mu) * inv * g + bt;

    // f for this thread's i-th chunk: f = i*16 + (tid>>4); as a lane index
    // within this wave: i*16 + wave*4 + (lane>>4) == i*16 + fbase.
    const int fbase = ((tid >> 6) << 2) + (lane >> 4);

    // --- Emit 4096 floats as 1024 nontemporal float4 stores (4 / thread) ---
    f4* __restrict__ o4 = (f4*)(out + (size_t)row * 4096);
    #pragma unroll
    for (int i = 0; i < 4; ++i) {
        float xn = __shfl(xn_lane, i * 16 + fbase, 64);
        f4 r;
        r.x = fmaf(xn, wv[i].x, bv[i].x + ev[i].x);
        r.y = fmaf(xn, wv[i].y, bv[i].y + ev[i].y);
        r.z = fmaf(xn, wv[i].z, bv[i].z + ev[i].z);
        r.w = fmaf(xn, wv[i].w, bv[i].w + ev[i].w);
        __builtin_nontemporal_store(r, &o4[i * 256 + tid]);
    }
}

extern "C" void kernel_launch(void* const* d_in, const int* in_sizes, int n_in,
                              void* d_out, int out_size, void* d_ws, size_t ws_size,
                              hipStream_t stream) {
    const float* x     = (const float*)d_in[0];  // [4,4096,64]
    const float* gamma = (const float*)d_in[1];  // [64]
    const float* beta  = (const float*)d_in[2];  // [64]
    const float* w     = (const float*)d_in[3];  // [64,64]
    const float* pb    = (const float*)d_in[4];  // [64,64]
    const float* emb   = (const float*)d_in[5];  // [64,64]
    float* out = (float*)d_out;

    const int rows = 4 * 4096;  // B * N
    pte_kernel<<<rows, 256, 0, stream>>>(x, gamma, beta, w, pb, emb, out);
}